// Round 4
// baseline (321.574 us; speedup 1.0000x reference)
//
#include <hip/hip_runtime.h>

// Problem constants
#define BB 8
#define TT 1024
#define CC 768
#define HH 12
#define DD 64
// M = BB*TT = 8192, K = CC = 768, N_qkv = 3*CC = 2304

typedef float f32x4 __attribute__((ext_vector_type(4)));
typedef short s16x8 __attribute__((ext_vector_type(8)));

#define SCALE2 0.18033688011112042f   // (1/sqrt(64)) * log2(e), folded into q

__device__ __forceinline__ unsigned short f2bf(float f) {
  unsigned u = __builtin_bit_cast(unsigned, f);
  u += 0x7fffu + ((u >> 16) & 1u);   // RNE
  return (unsigned short)(u >> 16);
}

#define GLOAD_LDS16(gsrc, ldst)                                                     \
  __builtin_amdgcn_global_load_lds(                                                 \
      (const __attribute__((address_space(1))) void*)(gsrc),                        \
      (__attribute__((address_space(3))) void*)(ldst), 16, 0, 0)

// ---------------------------------------------------------------- cast f32->bf16
__global__ __launch_bounds__(256) void cast_f32_bf16(const float* __restrict__ src,
                                                     unsigned short* __restrict__ dst,
                                                     int n4) {
  int i = blockIdx.x * 256 + threadIdx.x;
  if (i >= n4) return;
  float4 v = ((const float4*)src)[i];
  ushort4 o;
  o.x = f2bf(v.x); o.y = f2bf(v.y); o.z = f2bf(v.z); o.w = f2bf(v.w);
  ((ushort4*)dst)[i] = o;
}

// ------------------------------------------- transpose Wq/Wk/Wv -> WT[2304][768]
__global__ __launch_bounds__(256) void transpose_w(const float* __restrict__ Wq,
                                                   const float* __restrict__ Wk,
                                                   const float* __restrict__ Wv,
                                                   unsigned short* __restrict__ WT) {
  __shared__ float tile[32][33];
  int bid = blockIdx.x;
  int which = bid / (24 * 24);
  int rem = bid % (24 * 24);
  int cb = (rem / 24) * 32, nb = (rem % 24) * 32;
  const float* W = (which == 0) ? Wq : (which == 1) ? Wk : Wv;
  int t = threadIdx.x;
  int j = t & 31, i0 = t >> 5;
  #pragma unroll
  for (int rr = 0; rr < 4; ++rr) {
    int i = i0 + rr * 8;
    tile[i][j] = W[(size_t)(cb + i) * CC + nb + j];
  }
  __syncthreads();
  #pragma unroll
  for (int rr = 0; rr < 4; ++rr) {
    int i = i0 + rr * 8;
    WT[(size_t)(which * CC + nb + i) * CC + cb + j] = f2bf(tile[j][i]);
  }
}

// --------------------------------------------------------- GEMM mainloop (m97)
__device__ __forceinline__ void gemm_tile(const unsigned short* __restrict__ A,
                                          const unsigned short* __restrict__ BT,
                                          int m0, int n0,
                                          unsigned short* As, unsigned short* Bs,
                                          f32x4 acc[4][4]) {
  const int t = threadIdx.x, lane = t & 63, w = t >> 6;
  const int g = lane >> 4, c = lane & 15;
  const int wr = w >> 1, wc = w & 1;
  const int srow = lane >> 3;
  const int scol = (lane & 7) * 8;
  #pragma unroll 1
  for (int kt = 0; kt < CC; kt += 64) {
    __syncthreads();
    #pragma unroll
    for (int p = 0; p < 4; ++p) {
      int row = p * 32 + w * 8 + srow;
      GLOAD_LDS16(A + (size_t)(m0 + row) * CC + kt + scol, As + (p * 32 + w * 8) * 64);
      GLOAD_LDS16(BT + (size_t)(n0 + row) * CC + kt + scol, Bs + (p * 32 + w * 8) * 64);
    }
    __syncthreads();
    #pragma unroll
    for (int ks = 0; ks < 2; ++ks) {
      s16x8 a[4], b[4];
      #pragma unroll
      for (int i = 0; i < 4; ++i) {
        a[i] = *(const s16x8*)(As + (wr * 64 + i * 16 + c) * 64 + ks * 32 + g * 8);
        b[i] = *(const s16x8*)(Bs + (wc * 64 + i * 16 + c) * 64 + ks * 32 + g * 8);
      }
      #pragma unroll
      for (int i = 0; i < 4; ++i)
        #pragma unroll
        for (int j = 0; j < 4; ++j)
          acc[i][j] = __builtin_amdgcn_mfma_f32_16x16x32_bf16(a[i], b[j], acc[i][j], 0, 0, 0);
    }
  }
}

// --------------------------------------------------------------- QKV projection
// Writes q (pre-scaled by SCALE2), k as [b][h][t][d], v transposed [b][h][d][t].
__global__ __launch_bounds__(256) void gemm_qkv(const unsigned short* __restrict__ xb,
                                                const unsigned short* __restrict__ WT,
                                                unsigned short* __restrict__ qb,
                                                unsigned short* __restrict__ kb,
                                                unsigned short* __restrict__ vT) {
  __shared__ unsigned short As[128 * 64], Bs[128 * 64];
  int bid = blockIdx.x;
  int bm = bid % 64, bn = bid / 64;
  int m0 = bm * 128, n0 = bn * 128;
  f32x4 acc[4][4];
  #pragma unroll
  for (int i = 0; i < 4; ++i)
    #pragma unroll
    for (int j = 0; j < 4; ++j)
      acc[i][j] = (f32x4){0.f, 0.f, 0.f, 0.f};
  gemm_tile(xb, WT, m0, n0, As, Bs, acc);

  const int t = threadIdx.x, lane = t & 63, w = t >> 6;
  const int g = lane >> 4, c = lane & 15;
  const int wr = w >> 1, wc = w & 1;
  #pragma unroll
  for (int i = 0; i < 4; ++i) {
    int mrow = m0 + wr * 64 + i * 16 + g * 4;
    int b = mrow >> 10, tt_ = mrow & 1023;
    #pragma unroll
    for (int j = 0; j < 4; ++j) {
      int nbv = n0 + wc * 64 + j * 16;
      int which = nbv / CC;
      int rm = nbv - which * CC;
      int h = rm >> 6, d0 = rm & 63;
      if (which == 2) {
        ushort4 pk;
        pk.x = f2bf(acc[i][j][0]); pk.y = f2bf(acc[i][j][1]);
        pk.z = f2bf(acc[i][j][2]); pk.w = f2bf(acc[i][j][3]);
        *(ushort4*)(vT + ((size_t)(b * HH + h) * DD + d0 + c) * TT + tt_) = pk;
      } else {
        float sc = which ? 1.0f : SCALE2;   // fold softmax scale into q
        unsigned short* dst = (which ? kb : qb) +
                              ((size_t)(b * HH + h) * TT + tt_) * DD + d0 + c;
        dst[0]      = f2bf(acc[i][j][0] * sc);
        dst[DD]     = f2bf(acc[i][j][1] * sc);
        dst[2 * DD] = f2bf(acc[i][j][2] * sc);
        dst[3 * DD] = f2bf(acc[i][j][3] * sc);
      }
    }
  }
}

// ------------------------------------------------------ attn softmax sub-step
// Online softmax over a 64-col chunk for one 16-row strip; P -> swizzled LDS.
// lp is a PER-LANE partial sum (cross-lane reduce deferred to epilogue).
__device__ __forceinline__ void softmax_tile(f32x4 accs[4], float m[4], float lp[4],
                                             f32x4 acco[4], int q0, int s0, bool diag,
                                             int g, int c, unsigned short* Pst) {
  if (diag) {
    #pragma unroll
    for (int nj = 0; nj < 4; ++nj)
      #pragma unroll
      for (int r = 0; r < 4; ++r)
        if (s0 + nj * 16 + c > q0 + g * 4 + r) accs[nj][r] = -1e30f;
  }
  float fs[4];
  #pragma unroll
  for (int r = 0; r < 4; ++r) {
    float mx = fmaxf(fmaxf(accs[0][r], accs[1][r]), fmaxf(accs[2][r], accs[3][r]));
    mx = fmaxf(mx, __shfl_xor(mx, 1));
    mx = fmaxf(mx, __shfl_xor(mx, 2));
    mx = fmaxf(mx, __shfl_xor(mx, 4));
    mx = fmaxf(mx, __shfl_xor(mx, 8));
    float newm = fmaxf(m[r], mx);
    fs[r] = __builtin_amdgcn_exp2f(m[r] - newm);
    m[r] = newm;
  }
  #pragma unroll
  for (int nj = 0; nj < 4; ++nj)
    #pragma unroll
    for (int r = 0; r < 4; ++r)
      accs[nj][r] = __builtin_amdgcn_exp2f(accs[nj][r] - m[r]);
  #pragma unroll
  for (int r = 0; r < 4; ++r) {
    float s = (accs[0][r] + accs[1][r]) + (accs[2][r] + accs[3][r]);
    lp[r] = lp[r] * fs[r] + s;
    #pragma unroll
    for (int nj = 0; nj < 4; ++nj) acco[nj][r] *= fs[r];
  }
  #pragma unroll
  for (int nj = 0; nj < 4; ++nj)
    #pragma unroll
    for (int r = 0; r < 4; ++r) {
      int tr = g * 4 + r;
      Pst[(tr * 64 + nj * 16 + c) ^ ((tr & 7) << 3)] = f2bf(accs[nj][r]);
    }
}

// ------------------------------------------------------------- flash attention
// Dual-strip: each wave owns strips (p, 63-p); one shared k-loop loads each
// K/V tile ONCE and feeds both strips (strip p's tiles are a prefix of strip
// 63-p's). V frags issued before softmax to hide latency. grid = 96 bh * 8.
__global__ __launch_bounds__(256, 4) void attn(const unsigned short* __restrict__ qb,
                                               const unsigned short* __restrict__ kb,
                                               const unsigned short* __restrict__ vT,
                                               unsigned short* __restrict__ ao) {
  __shared__ unsigned short P[4][2][16 * 64];
  int bid = blockIdx.x;
  int sub = bid & 7, bh = bid >> 3;
  int b = bh / HH, h = bh % HH;
  int t = threadIdx.x, lane = t & 63, w = t >> 6;
  int g = lane >> 4, c = lane & 15;
  unsigned short* PA = P[w][0];
  unsigned short* PB = P[w][1];
  const unsigned short* Q = qb + (size_t)bh * TT * DD;
  const unsigned short* K = kb + (size_t)bh * TT * DD;
  const unsigned short* V = vT + (size_t)bh * DD * TT;
  int p = sub * 4 + w;                 // 0..31
  int qA = p * 16, qB = (63 - p) * 16; // strip A small, strip B large
  int ntA = (qA + 79) >> 6, ntB = (qB + 79) >> 6;

  s16x8 aqA[2], aqB[2];
  #pragma unroll
  for (int ks = 0; ks < 2; ++ks) {
    aqA[ks] = *(const s16x8*)(Q + (size_t)(qA + c) * DD + ks * 32 + g * 8);
    aqB[ks] = *(const s16x8*)(Q + (size_t)(qB + c) * DD + ks * 32 + g * 8);
  }

  f32x4 accoA[4], accoB[4];
  float mA[4], lA[4], mB[4], lB[4];
  #pragma unroll
  for (int nj = 0; nj < 4; ++nj) {
    accoA[nj] = (f32x4){0.f, 0.f, 0.f, 0.f};
    accoB[nj] = (f32x4){0.f, 0.f, 0.f, 0.f};
  }
  #pragma unroll
  for (int r = 0; r < 4; ++r) {
    mA[r] = -1e30f; lA[r] = 0.f;
    mB[r] = -1e30f; lB[r] = 0.f;
  }

  #pragma unroll 1
  for (int kt = 0; kt < ntB; ++kt) {
    int s0 = kt * 64;
    bool dual = (kt < ntA);
    f32x4 accsA[4], accsB[4];
    #pragma unroll
    for (int nj = 0; nj < 4; ++nj) {
      accsA[nj] = (f32x4){0.f, 0.f, 0.f, 0.f};
      accsB[nj] = (f32x4){0.f, 0.f, 0.f, 0.f};
    }

    // S = Q K^T for both strips off ONE K-tile load
    #pragma unroll
    for (int ks = 0; ks < 2; ++ks) {
      s16x8 bk[4];
      #pragma unroll
      for (int nj = 0; nj < 4; ++nj)
        bk[nj] = *(const s16x8*)(K + (size_t)(s0 + nj * 16 + c) * DD + ks * 32 + g * 8);
      #pragma unroll
      for (int nj = 0; nj < 4; ++nj)
        accsB[nj] = __builtin_amdgcn_mfma_f32_16x16x32_bf16(aqB[ks], bk[nj],
                                                            accsB[nj], 0, 0, 0);
      if (dual) {
        #pragma unroll
        for (int nj = 0; nj < 4; ++nj)
          accsA[nj] = __builtin_amdgcn_mfma_f32_16x16x32_bf16(aqA[ks], bk[nj],
                                                              accsA[nj], 0, 0, 0);
      }
    }

    // V frags: issue loads before softmax so latency hides under it
    s16x8 bv0[4], bv1[4];
    #pragma unroll
    for (int nj = 0; nj < 4; ++nj)
      bv0[nj] = *(const s16x8*)(V + (size_t)(nj * 16 + c) * TT + s0 + g * 8);

    if (dual) softmax_tile(accsA, mA, lA, accoA, qA, s0, kt == ntA - 1, g, c, PA);

    #pragma unroll
    for (int nj = 0; nj < 4; ++nj)
      bv1[nj] = *(const s16x8*)(V + (size_t)(nj * 16 + c) * TT + s0 + 32 + g * 8);

    softmax_tile(accsB, mB, lB, accoB, qB, s0, kt == ntB - 1, g, c, PB);
    asm volatile("" ::: "memory");  // P writes before P reads

    // O += P V for both strips off the shared V tile
    {
      s16x8 paB0 = *(const s16x8*)(PB + ((c * 64 + g * 8) ^ ((c & 7) << 3)));
      s16x8 paB1 = *(const s16x8*)(PB + ((c * 64 + 32 + g * 8) ^ ((c & 7) << 3)));
      #pragma unroll
      for (int nj = 0; nj < 4; ++nj)
        accoB[nj] = __builtin_amdgcn_mfma_f32_16x16x32_bf16(paB0, bv0[nj],
                                                            accoB[nj], 0, 0, 0);
      #pragma unroll
      for (int nj = 0; nj < 4; ++nj)
        accoB[nj] = __builtin_amdgcn_mfma_f32_16x16x32_bf16(paB1, bv1[nj],
                                                            accoB[nj], 0, 0, 0);
      if (dual) {
        s16x8 paA0 = *(const s16x8*)(PA + ((c * 64 + g * 8) ^ ((c & 7) << 3)));
        s16x8 paA1 = *(const s16x8*)(PA + ((c * 64 + 32 + g * 8) ^ ((c & 7) << 3)));
        #pragma unroll
        for (int nj = 0; nj < 4; ++nj)
          accoA[nj] = __builtin_amdgcn_mfma_f32_16x16x32_bf16(paA0, bv0[nj],
                                                              accoA[nj], 0, 0, 0);
        #pragma unroll
        for (int nj = 0; nj < 4; ++nj)
          accoA[nj] = __builtin_amdgcn_mfma_f32_16x16x32_bf16(paA1, bv1[nj],
                                                              accoA[nj], 0, 0, 0);
      }
    }
    asm volatile("" ::: "memory");
  }

  // epilogue: deferred l-reduction (once per strip) + O/l writeback
  #pragma unroll
  for (int r = 0; r < 4; ++r) {
    float sA = lA[r];
    sA += __shfl_xor(sA, 1);
    sA += __shfl_xor(sA, 2);
    sA += __shfl_xor(sA, 4);
    sA += __shfl_xor(sA, 8);
    float invA = 1.0f / sA;
    int trA = qA + g * 4 + r;
    size_t rowbA = ((size_t)b * TT + trA) * CC + h * DD;
    #pragma unroll
    for (int nj = 0; nj < 4; ++nj)
      ao[rowbA + nj * 16 + c] = f2bf(accoA[nj][r] * invA);

    float sB = lB[r];
    sB += __shfl_xor(sB, 1);
    sB += __shfl_xor(sB, 2);
    sB += __shfl_xor(sB, 4);
    sB += __shfl_xor(sB, 8);
    float invB = 1.0f / sB;
    int trB = qB + g * 4 + r;
    size_t rowbB = ((size_t)b * TT + trB) * CC + h * DD;
    #pragma unroll
    for (int nj = 0; nj < 4; ++nj)
      ao[rowbB + nj * 16 + c] = f2bf(accoB[nj][r] * invB);
  }
}

// -------------------------------------------------------- output projection
__global__ __launch_bounds__(256) void gemm_proj(const unsigned short* __restrict__ ao,
                                                 const unsigned short* __restrict__ WpB,
                                                 const float* __restrict__ bp,
                                                 float* __restrict__ out) {
  __shared__ unsigned short As[128 * 64], Bs[128 * 64];
  int bid = blockIdx.x;
  int bm = bid % 64, bn = bid / 64;
  int m0 = bm * 128, n0 = bn * 128;
  f32x4 acc[4][4];
  #pragma unroll
  for (int i = 0; i < 4; ++i)
    #pragma unroll
    for (int j = 0; j < 4; ++j)
      acc[i][j] = (f32x4){0.f, 0.f, 0.f, 0.f};
  gemm_tile(ao, WpB, m0, n0, As, Bs, acc);

  const int t = threadIdx.x, lane = t & 63, w = t >> 6;
  const int g = lane >> 4, c = lane & 15;
  const int wr = w >> 1, wc = w & 1;
  #pragma unroll
  for (int i = 0; i < 4; ++i) {
    int mrow = m0 + wr * 64 + i * 16 + g * 4;
    #pragma unroll
    for (int j = 0; j < 4; ++j) {
      int nn = n0 + wc * 64 + j * 16 + c;
      float bias = bp[nn];
      float* dst = out + (size_t)mrow * CC + nn;
      dst[0]        = acc[i][j][0] + bias;
      dst[CC]       = acc[i][j][1] + bias;
      dst[2 * CC]   = acc[i][j][2] + bias;
      dst[3 * CC]   = acc[i][j][3] + bias;
    }
  }
}

// ------------------------------------------------------------------- launcher
extern "C" void kernel_launch(void* const* d_in, const int* in_sizes, int n_in,
                              void* d_out, int out_size, void* d_ws, size_t ws_size,
                              hipStream_t stream) {
  (void)in_sizes; (void)n_in; (void)out_size; (void)ws_size;
  const float* x  = (const float*)d_in[0];
  const float* Wq = (const float*)d_in[1];
  const float* Wk = (const float*)d_in[2];
  const float* Wv = (const float*)d_in[3];
  const float* Wp = (const float*)d_in[4];
  const float* bp = (const float*)d_in[5];
  float* out = (float*)d_out;

  char* ws = (char*)d_ws;
  unsigned short* xb  = (unsigned short*)(ws);                       // 8192x768
  unsigned short* WT  = (unsigned short*)(ws + 12582912);            // 2304x768
  unsigned short* WpB = (unsigned short*)(ws + 16121856);            // 768x768
  unsigned short* qb  = (unsigned short*)(ws + 17301504);            // [B][H][T][D]
  unsigned short* kb  = (unsigned short*)(ws + 29884416);            // [B][H][T][D]
  unsigned short* vT  = (unsigned short*)(ws + 42467328);            // [B][H][D][T]
  unsigned short* aob = (unsigned short*)(ws + 55050240);            // 8192x768
  // total = 67633152 bytes

  cast_f32_bf16<<<6144, 256, 0, stream>>>(x, xb, 1572864);
  cast_f32_bf16<<<576, 256, 0, stream>>>(Wp, WpB, 147456);
  transpose_w<<<1728, 256, 0, stream>>>(Wq, Wk, Wv, WT);
  gemm_qkv<<<1152, 256, 0, stream>>>(xb, WT, qb, kb, vT);
  attn<<<768, 256, 0, stream>>>(qb, kb, vT, aob);
  gemm_proj<<<384, 256, 0, stream>>>(aob, WpB, bp, out);
}

// Round 5
// 269.980 us; speedup vs baseline: 1.1911x; 1.1911x over previous
//
#include <hip/hip_runtime.h>

// Problem constants
#define BB 8
#define TT 1024
#define CC 768
#define HH 12
#define DD 64
// M = BB*TT = 8192, K = CC = 768, N_qkv = 3*CC = 2304

typedef float f32x4 __attribute__((ext_vector_type(4)));
typedef short s16x8 __attribute__((ext_vector_type(8)));

#define SCALE2 0.18033688011112042f   // (1/sqrt(64)) * log2(e), folded into q

__device__ __forceinline__ unsigned short f2bf(float f) {
  unsigned u = __builtin_bit_cast(unsigned, f);
  u += 0x7fffu + ((u >> 16) & 1u);   // RNE
  return (unsigned short)(u >> 16);
}

#define GLOAD_LDS16(gsrc, ldst)                                                     \
  __builtin_amdgcn_global_load_lds(                                                 \
      (const __attribute__((address_space(1))) void*)(gsrc),                        \
      (__attribute__((address_space(3))) void*)(ldst), 16, 0, 0)

// ---------------------------------------------------------------- cast f32->bf16
__global__ __launch_bounds__(256) void cast_f32_bf16(const float* __restrict__ src,
                                                     unsigned short* __restrict__ dst,
                                                     int n4) {
  int i = blockIdx.x * 256 + threadIdx.x;
  if (i >= n4) return;
  float4 v = ((const float4*)src)[i];
  ushort4 o;
  o.x = f2bf(v.x); o.y = f2bf(v.y); o.z = f2bf(v.z); o.w = f2bf(v.w);
  ((ushort4*)dst)[i] = o;
}

// ------------------------------------------- transpose Wq/Wk/Wv -> WT[2304][768]
__global__ __launch_bounds__(256) void transpose_w(const float* __restrict__ Wq,
                                                   const float* __restrict__ Wk,
                                                   const float* __restrict__ Wv,
                                                   unsigned short* __restrict__ WT) {
  __shared__ float tile[32][33];
  int bid = blockIdx.x;
  int which = bid / (24 * 24);
  int rem = bid % (24 * 24);
  int cb = (rem / 24) * 32, nb = (rem % 24) * 32;
  const float* W = (which == 0) ? Wq : (which == 1) ? Wk : Wv;
  int t = threadIdx.x;
  int j = t & 31, i0 = t >> 5;
  #pragma unroll
  for (int rr = 0; rr < 4; ++rr) {
    int i = i0 + rr * 8;
    tile[i][j] = W[(size_t)(cb + i) * CC + nb + j];
  }
  __syncthreads();
  #pragma unroll
  for (int rr = 0; rr < 4; ++rr) {
    int i = i0 + rr * 8;
    WT[(size_t)(which * CC + nb + i) * CC + cb + j] = f2bf(tile[j][i]);
  }
}

// --------------------------------------------------------- GEMM mainloop (m97)
__device__ __forceinline__ void gemm_tile(const unsigned short* __restrict__ A,
                                          const unsigned short* __restrict__ BT,
                                          int m0, int n0,
                                          unsigned short* As, unsigned short* Bs,
                                          f32x4 acc[4][4]) {
  const int t = threadIdx.x, lane = t & 63, w = t >> 6;
  const int g = lane >> 4, c = lane & 15;
  const int wr = w >> 1, wc = w & 1;
  const int srow = lane >> 3;
  const int scol = (lane & 7) * 8;
  #pragma unroll 1
  for (int kt = 0; kt < CC; kt += 64) {
    __syncthreads();
    #pragma unroll
    for (int p = 0; p < 4; ++p) {
      int row = p * 32 + w * 8 + srow;
      GLOAD_LDS16(A + (size_t)(m0 + row) * CC + kt + scol, As + (p * 32 + w * 8) * 64);
      GLOAD_LDS16(BT + (size_t)(n0 + row) * CC + kt + scol, Bs + (p * 32 + w * 8) * 64);
    }
    __syncthreads();
    #pragma unroll
    for (int ks = 0; ks < 2; ++ks) {
      s16x8 a[4], b[4];
      #pragma unroll
      for (int i = 0; i < 4; ++i) {
        a[i] = *(const s16x8*)(As + (wr * 64 + i * 16 + c) * 64 + ks * 32 + g * 8);
        b[i] = *(const s16x8*)(Bs + (wc * 64 + i * 16 + c) * 64 + ks * 32 + g * 8);
      }
      #pragma unroll
      for (int i = 0; i < 4; ++i)
        #pragma unroll
        for (int j = 0; j < 4; ++j)
          acc[i][j] = __builtin_amdgcn_mfma_f32_16x16x32_bf16(a[i], b[j], acc[i][j], 0, 0, 0);
    }
  }
}

// --------------------------------------------------------------- QKV projection
// Writes q (pre-scaled by SCALE2), k as [b][h][t][d], v transposed [b][h][d][t].
__global__ __launch_bounds__(256) void gemm_qkv(const unsigned short* __restrict__ xb,
                                                const unsigned short* __restrict__ WT,
                                                unsigned short* __restrict__ qb,
                                                unsigned short* __restrict__ kb,
                                                unsigned short* __restrict__ vT) {
  __shared__ unsigned short As[128 * 64], Bs[128 * 64];
  int bid = blockIdx.x;
  int bm = bid % 64, bn = bid / 64;
  int m0 = bm * 128, n0 = bn * 128;
  f32x4 acc[4][4];
  #pragma unroll
  for (int i = 0; i < 4; ++i)
    #pragma unroll
    for (int j = 0; j < 4; ++j)
      acc[i][j] = (f32x4){0.f, 0.f, 0.f, 0.f};
  gemm_tile(xb, WT, m0, n0, As, Bs, acc);

  const int t = threadIdx.x, lane = t & 63, w = t >> 6;
  const int g = lane >> 4, c = lane & 15;
  const int wr = w >> 1, wc = w & 1;
  #pragma unroll
  for (int i = 0; i < 4; ++i) {
    int mrow = m0 + wr * 64 + i * 16 + g * 4;
    int b = mrow >> 10, tt_ = mrow & 1023;
    #pragma unroll
    for (int j = 0; j < 4; ++j) {
      int nbv = n0 + wc * 64 + j * 16;
      int which = nbv / CC;
      int rm = nbv - which * CC;
      int h = rm >> 6, d0 = rm & 63;
      if (which == 2) {
        ushort4 pk;
        pk.x = f2bf(acc[i][j][0]); pk.y = f2bf(acc[i][j][1]);
        pk.z = f2bf(acc[i][j][2]); pk.w = f2bf(acc[i][j][3]);
        *(ushort4*)(vT + ((size_t)(b * HH + h) * DD + d0 + c) * TT + tt_) = pk;
      } else {
        float sc = which ? 1.0f : SCALE2;   // fold softmax scale into q
        unsigned short* dst = (which ? kb : qb) +
                              ((size_t)(b * HH + h) * TT + tt_) * DD + d0 + c;
        dst[0]      = f2bf(acc[i][j][0] * sc);
        dst[DD]     = f2bf(acc[i][j][1] * sc);
        dst[2 * DD] = f2bf(acc[i][j][2] * sc);
        dst[3 * DD] = f2bf(acc[i][j][3] * sc);
      }
    }
  }
}

// ------------------------------------------------------ attn softmax sub-step
// Online softmax over a 64-col chunk for one 16-row strip; P -> swizzled LDS.
// lp is a PER-LANE partial sum (cross-lane reduce deferred to epilogue).
__device__ __forceinline__ void softmax_tile(f32x4 accs[4], float m[4], float lp[4],
                                             f32x4 acco[4], int q0, int s0, bool diag,
                                             int g, int c, unsigned short* Pst) {
  if (diag) {
    #pragma unroll
    for (int nj = 0; nj < 4; ++nj)
      #pragma unroll
      for (int r = 0; r < 4; ++r)
        if (s0 + nj * 16 + c > q0 + g * 4 + r) accs[nj][r] = -1e30f;
  }
  float fs[4];
  #pragma unroll
  for (int r = 0; r < 4; ++r) {
    float mx = fmaxf(fmaxf(accs[0][r], accs[1][r]), fmaxf(accs[2][r], accs[3][r]));
    mx = fmaxf(mx, __shfl_xor(mx, 1));
    mx = fmaxf(mx, __shfl_xor(mx, 2));
    mx = fmaxf(mx, __shfl_xor(mx, 4));
    mx = fmaxf(mx, __shfl_xor(mx, 8));
    float newm = fmaxf(m[r], mx);
    fs[r] = __builtin_amdgcn_exp2f(m[r] - newm);
    m[r] = newm;
  }
  #pragma unroll
  for (int nj = 0; nj < 4; ++nj)
    #pragma unroll
    for (int r = 0; r < 4; ++r)
      accs[nj][r] = __builtin_amdgcn_exp2f(accs[nj][r] - m[r]);
  #pragma unroll
  for (int r = 0; r < 4; ++r) {
    float s = (accs[0][r] + accs[1][r]) + (accs[2][r] + accs[3][r]);
    lp[r] = lp[r] * fs[r] + s;
    #pragma unroll
    for (int nj = 0; nj < 4; ++nj) acco[nj][r] *= fs[r];
  }
  #pragma unroll
  for (int nj = 0; nj < 4; ++nj)
    #pragma unroll
    for (int r = 0; r < 4; ++r) {
      int tr = g * 4 + r;
      Pst[(tr * 64 + nj * 16 + c) ^ ((tr & 7) << 3)] = f2bf(accs[nj][r]);
    }
}

// ------------------------------------------------------------- flash attention
// R3 balanced strip-pair structure + (a) XCD-grouping remap so all 8 blocks of
// one bh share one XCD's L2 (12 bh/XCD -> 3MB K/V working set), (b) K-tile
// double-buffer + early V loads so global latency hides under softmax VALU.
__global__ __launch_bounds__(256, 2) void attn(const unsigned short* __restrict__ qb,
                                               const unsigned short* __restrict__ kb,
                                               const unsigned short* __restrict__ vT,
                                               unsigned short* __restrict__ ao) {
  __shared__ unsigned short P[4][16 * 64];
  int bid0 = blockIdx.x;
  // remap: bid = sub*96 + m12*8 + xcd  ->  all subs of bh=(xcd*12+m12) have the
  // same bid%8, i.e. the same XCD under round-robin dispatch. Bijective on 768.
  int xcd = bid0 & 7, slot = bid0 >> 3;
  int m12 = slot % 12, sub = slot / 12;
  int bh = xcd * 12 + m12;
  int b = bh / HH, h = bh % HH;
  int t = threadIdx.x, lane = t & 63, w = t >> 6;
  int g = lane >> 4, c = lane & 15;
  unsigned short* Pw = P[w];
  const unsigned short* Q = qb + (size_t)bh * TT * DD;
  const unsigned short* K = kb + (size_t)bh * TT * DD;
  const unsigned short* V = vT + (size_t)bh * DD * TT;
  int p = sub * 4 + w;   // 0..31

  #pragma unroll 1
  for (int half = 0; half < 2; ++half) {
    int strip = half ? (63 - p) : p;
    int q0 = strip * 16;

    s16x8 aq[2];
    #pragma unroll
    for (int ks = 0; ks < 2; ++ks)
      aq[ks] = *(const s16x8*)(Q + (size_t)(q0 + c) * DD + ks * 32 + g * 8);

    f32x4 acco[4];
    float mrow[4], lrow[4];
    #pragma unroll
    for (int nj = 0; nj < 4; ++nj) acco[nj] = (f32x4){0.f, 0.f, 0.f, 0.f};
    #pragma unroll
    for (int r = 0; r < 4; ++r) { mrow[r] = -1e30f; lrow[r] = 0.f; }

    int ntile = (q0 + 79) >> 6;   // tiles of 64 cols covering rows q0..q0+15

    // preload K frags for tile 0
    s16x8 bk[2][4];
    #pragma unroll
    for (int ks = 0; ks < 2; ++ks)
      #pragma unroll
      for (int nj = 0; nj < 4; ++nj)
        bk[ks][nj] = *(const s16x8*)(K + (size_t)(nj * 16 + c) * DD + ks * 32 + g * 8);

    #pragma unroll 1
    for (int kt = 0; kt < ntile; ++kt) {
      int s0 = kt * 64;
      f32x4 accs[4];
      #pragma unroll
      for (int nj = 0; nj < 4; ++nj) accs[nj] = (f32x4){0.f, 0.f, 0.f, 0.f};

      // S = Q K^T from resident frags (q pre-scaled)
      #pragma unroll
      for (int ks = 0; ks < 2; ++ks)
        #pragma unroll
        for (int nj = 0; nj < 4; ++nj)
          accs[nj] = __builtin_amdgcn_mfma_f32_16x16x32_bf16(aq[ks], bk[ks][nj],
                                                             accs[nj], 0, 0, 0);

      // issue V loads for THIS tile + K loads for NEXT tile; both in flight
      // during the softmax VALU phase below.
      s16x8 bv[2][4];
      #pragma unroll
      for (int ks = 0; ks < 2; ++ks)
        #pragma unroll
        for (int nj = 0; nj < 4; ++nj)
          bv[ks][nj] = *(const s16x8*)(V + (size_t)(nj * 16 + c) * TT +
                                       s0 + ks * 32 + g * 8);
      if (kt + 1 < ntile) {
        #pragma unroll
        for (int ks = 0; ks < 2; ++ks)
          #pragma unroll
          for (int nj = 0; nj < 4; ++nj)
            bk[ks][nj] = *(const s16x8*)(K + (size_t)(s0 + 64 + nj * 16 + c) * DD +
                                         ks * 32 + g * 8);
      }

      softmax_tile(accs, mrow, lrow, acco, q0, s0, kt == ntile - 1, g, c, Pw);
      asm volatile("" ::: "memory");  // P writes before P reads

      // O += P V
      #pragma unroll
      for (int ks = 0; ks < 2; ++ks) {
        s16x8 pa = *(const s16x8*)(Pw + ((c * 64 + ks * 32 + g * 8) ^ ((c & 7) << 3)));
        #pragma unroll
        for (int nj = 0; nj < 4; ++nj)
          acco[nj] = __builtin_amdgcn_mfma_f32_16x16x32_bf16(pa, bv[ks][nj],
                                                             acco[nj], 0, 0, 0);
      }
      asm volatile("" ::: "memory");
    }

    // epilogue: deferred l-reduction + O/l writeback
    #pragma unroll
    for (int r = 0; r < 4; ++r) {
      float s = lrow[r];
      s += __shfl_xor(s, 1);
      s += __shfl_xor(s, 2);
      s += __shfl_xor(s, 4);
      s += __shfl_xor(s, 8);
      float inv = 1.0f / s;
      int trow = q0 + g * 4 + r;
      size_t rowb = ((size_t)b * TT + trow) * CC + h * DD;
      #pragma unroll
      for (int nj = 0; nj < 4; ++nj)
        ao[rowb + nj * 16 + c] = f2bf(acco[nj][r] * inv);
    }
  }
}

// -------------------------------------------------------- output projection
__global__ __launch_bounds__(256) void gemm_proj(const unsigned short* __restrict__ ao,
                                                 const unsigned short* __restrict__ WpB,
                                                 const float* __restrict__ bp,
                                                 float* __restrict__ out) {
  __shared__ unsigned short As[128 * 64], Bs[128 * 64];
  int bid = blockIdx.x;
  int bm = bid % 64, bn = bid / 64;
  int m0 = bm * 128, n0 = bn * 128;
  f32x4 acc[4][4];
  #pragma unroll
  for (int i = 0; i < 4; ++i)
    #pragma unroll
    for (int j = 0; j < 4; ++j)
      acc[i][j] = (f32x4){0.f, 0.f, 0.f, 0.f};
  gemm_tile(ao, WpB, m0, n0, As, Bs, acc);

  const int t = threadIdx.x, lane = t & 63, w = t >> 6;
  const int g = lane >> 4, c = lane & 15;
  const int wr = w >> 1, wc = w & 1;
  #pragma unroll
  for (int i = 0; i < 4; ++i) {
    int mrow = m0 + wr * 64 + i * 16 + g * 4;
    #pragma unroll
    for (int j = 0; j < 4; ++j) {
      int nn = n0 + wc * 64 + j * 16 + c;
      float bias = bp[nn];
      float* dst = out + (size_t)mrow * CC + nn;
      dst[0]        = acc[i][j][0] + bias;
      dst[CC]       = acc[i][j][1] + bias;
      dst[2 * CC]   = acc[i][j][2] + bias;
      dst[3 * CC]   = acc[i][j][3] + bias;
    }
  }
}

// ------------------------------------------------------------------- launcher
extern "C" void kernel_launch(void* const* d_in, const int* in_sizes, int n_in,
                              void* d_out, int out_size, void* d_ws, size_t ws_size,
                              hipStream_t stream) {
  (void)in_sizes; (void)n_in; (void)out_size; (void)ws_size;
  const float* x  = (const float*)d_in[0];
  const float* Wq = (const float*)d_in[1];
  const float* Wk = (const float*)d_in[2];
  const float* Wv = (const float*)d_in[3];
  const float* Wp = (const float*)d_in[4];
  const float* bp = (const float*)d_in[5];
  float* out = (float*)d_out;

  char* ws = (char*)d_ws;
  unsigned short* xb  = (unsigned short*)(ws);                       // 8192x768
  unsigned short* WT  = (unsigned short*)(ws + 12582912);            // 2304x768
  unsigned short* WpB = (unsigned short*)(ws + 16121856);            // 768x768
  unsigned short* qb  = (unsigned short*)(ws + 17301504);            // [B][H][T][D]
  unsigned short* kb  = (unsigned short*)(ws + 29884416);            // [B][H][T][D]
  unsigned short* vT  = (unsigned short*)(ws + 42467328);            // [B][H][D][T]
  unsigned short* aob = (unsigned short*)(ws + 55050240);            // 8192x768
  // total = 67633152 bytes

  cast_f32_bf16<<<6144, 256, 0, stream>>>(x, xb, 1572864);
  cast_f32_bf16<<<576, 256, 0, stream>>>(Wp, WpB, 147456);
  transpose_w<<<1728, 256, 0, stream>>>(Wq, Wk, Wv, WT);
  gemm_qkv<<<1152, 256, 0, stream>>>(xb, WT, qb, kb, vT);
  attn<<<768, 256, 0, stream>>>(qb, kb, vT, aob);
  gemm_proj<<<384, 256, 0, stream>>>(aob, WpB, bp, out);
}

// Round 7
// 268.344 us; speedup vs baseline: 1.1984x; 1.0061x over previous
//
#include <hip/hip_runtime.h>

// Problem constants
#define BB 8
#define TT 1024
#define CC 768
#define HH 12
#define DD 64
// M = BB*TT = 8192, K = CC = 768, N_qkv = 3*CC = 2304

typedef float f32x4 __attribute__((ext_vector_type(4)));
typedef short s16x8 __attribute__((ext_vector_type(8)));

#define SCALE2 0.18033688011112042f   // (1/sqrt(64)) * log2(e), folded into q

__device__ __forceinline__ unsigned short f2bf(float f) {
  unsigned u = __builtin_bit_cast(unsigned, f);
  u += 0x7fffu + ((u >> 16) & 1u);   // RNE
  return (unsigned short)(u >> 16);
}

#define GLOAD_LDS16(gsrc, ldst)                                                     \
  __builtin_amdgcn_global_load_lds(                                                 \
      (const __attribute__((address_space(1))) void*)(gsrc),                        \
      (__attribute__((address_space(3))) void*)(ldst), 16, 0, 0)

// ---------------------------------------------------------------- cast f32->bf16
__global__ __launch_bounds__(256) void cast_f32_bf16(const float* __restrict__ src,
                                                     unsigned short* __restrict__ dst,
                                                     int n4) {
  int i = blockIdx.x * 256 + threadIdx.x;
  if (i >= n4) return;
  float4 v = ((const float4*)src)[i];
  ushort4 o;
  o.x = f2bf(v.x); o.y = f2bf(v.y); o.z = f2bf(v.z); o.w = f2bf(v.w);
  ((ushort4*)dst)[i] = o;
}

// ------------------------------------------- transpose Wq/Wk/Wv -> WT[2304][768]
__global__ __launch_bounds__(256) void transpose_w(const float* __restrict__ Wq,
                                                   const float* __restrict__ Wk,
                                                   const float* __restrict__ Wv,
                                                   unsigned short* __restrict__ WT) {
  __shared__ float tile[32][33];
  int bid = blockIdx.x;
  int which = bid / (24 * 24);
  int rem = bid % (24 * 24);
  int cb = (rem / 24) * 32, nb = (rem % 24) * 32;
  const float* W = (which == 0) ? Wq : (which == 1) ? Wk : Wv;
  int t = threadIdx.x;
  int j = t & 31, i0 = t >> 5;
  #pragma unroll
  for (int rr = 0; rr < 4; ++rr) {
    int i = i0 + rr * 8;
    tile[i][j] = W[(size_t)(cb + i) * CC + nb + j];
  }
  __syncthreads();
  #pragma unroll
  for (int rr = 0; rr < 4; ++rr) {
    int i = i0 + rr * 8;
    WT[(size_t)(which * CC + nb + i) * CC + cb + j] = f2bf(tile[j][i]);
  }
}

// --------------------------------------------------------- GEMM mainloop (m97)
__device__ __forceinline__ void gemm_tile(const unsigned short* __restrict__ A,
                                          const unsigned short* __restrict__ BT,
                                          int m0, int n0,
                                          unsigned short* As, unsigned short* Bs,
                                          f32x4 acc[4][4]) {
  const int t = threadIdx.x, lane = t & 63, w = t >> 6;
  const int g = lane >> 4, c = lane & 15;
  const int wr = w >> 1, wc = w & 1;
  const int srow = lane >> 3;
  const int scol = (lane & 7) * 8;
  #pragma unroll 1
  for (int kt = 0; kt < CC; kt += 64) {
    __syncthreads();
    #pragma unroll
    for (int p = 0; p < 4; ++p) {
      int row = p * 32 + w * 8 + srow;
      GLOAD_LDS16(A + (size_t)(m0 + row) * CC + kt + scol, As + (p * 32 + w * 8) * 64);
      GLOAD_LDS16(BT + (size_t)(n0 + row) * CC + kt + scol, Bs + (p * 32 + w * 8) * 64);
    }
    __syncthreads();
    #pragma unroll
    for (int ks = 0; ks < 2; ++ks) {
      s16x8 a[4], b[4];
      #pragma unroll
      for (int i = 0; i < 4; ++i) {
        a[i] = *(const s16x8*)(As + (wr * 64 + i * 16 + c) * 64 + ks * 32 + g * 8);
        b[i] = *(const s16x8*)(Bs + (wc * 64 + i * 16 + c) * 64 + ks * 32 + g * 8);
      }
      #pragma unroll
      for (int i = 0; i < 4; ++i)
        #pragma unroll
        for (int j = 0; j < 4; ++j)
          acc[i][j] = __builtin_amdgcn_mfma_f32_16x16x32_bf16(a[i], b[j], acc[i][j], 0, 0, 0);
    }
  }
}

// --------------------------------------------------------------- QKV projection
// Writes q (pre-scaled by SCALE2), k as [b][h][t][d], v transposed [b][h][d][t].
__global__ __launch_bounds__(256) void gemm_qkv(const unsigned short* __restrict__ xb,
                                                const unsigned short* __restrict__ WT,
                                                unsigned short* __restrict__ qb,
                                                unsigned short* __restrict__ kb,
                                                unsigned short* __restrict__ vT) {
  __shared__ unsigned short As[128 * 64], Bs[128 * 64];
  int bid = blockIdx.x;
  int bm = bid % 64, bn = bid / 64;
  int m0 = bm * 128, n0 = bn * 128;
  f32x4 acc[4][4];
  #pragma unroll
  for (int i = 0; i < 4; ++i)
    #pragma unroll
    for (int j = 0; j < 4; ++j)
      acc[i][j] = (f32x4){0.f, 0.f, 0.f, 0.f};
  gemm_tile(xb, WT, m0, n0, As, Bs, acc);

  const int t = threadIdx.x, lane = t & 63, w = t >> 6;
  const int g = lane >> 4, c = lane & 15;
  const int wr = w >> 1, wc = w & 1;
  #pragma unroll
  for (int i = 0; i < 4; ++i) {
    int mrow = m0 + wr * 64 + i * 16 + g * 4;
    int b = mrow >> 10, tt_ = mrow & 1023;
    #pragma unroll
    for (int j = 0; j < 4; ++j) {
      int nbv = n0 + wc * 64 + j * 16;
      int which = nbv / CC;
      int rm = nbv - which * CC;
      int h = rm >> 6, d0 = rm & 63;
      if (which == 2) {
        ushort4 pk;
        pk.x = f2bf(acc[i][j][0]); pk.y = f2bf(acc[i][j][1]);
        pk.z = f2bf(acc[i][j][2]); pk.w = f2bf(acc[i][j][3]);
        *(ushort4*)(vT + ((size_t)(b * HH + h) * DD + d0 + c) * TT + tt_) = pk;
      } else {
        float sc = which ? 1.0f : SCALE2;   // fold softmax scale into q
        unsigned short* dst = (which ? kb : qb) +
                              ((size_t)(b * HH + h) * TT + tt_) * DD + d0 + c;
        dst[0]      = f2bf(acc[i][j][0] * sc);
        dst[DD]     = f2bf(acc[i][j][1] * sc);
        dst[2 * DD] = f2bf(acc[i][j][2] * sc);
        dst[3 * DD] = f2bf(acc[i][j][3] * sc);
      }
    }
  }
}

// ------------------------------------------------------ attn softmax sub-step
// Online softmax over a 64-col chunk for one 16-row strip; P -> swizzled LDS.
// lp is a PER-LANE partial sum (cross-lane reduce deferred to epilogue).
__device__ __forceinline__ void softmax_tile(f32x4 accs[4], float m[4], float lp[4],
                                             f32x4 acco[4], int q0, int s0, bool diag,
                                             int g, int c, unsigned short* Pst) {
  if (diag) {
    #pragma unroll
    for (int nj = 0; nj < 4; ++nj)
      #pragma unroll
      for (int r = 0; r < 4; ++r)
        if (s0 + nj * 16 + c > q0 + g * 4 + r) accs[nj][r] = -1e30f;
  }
  float fs[4];
  #pragma unroll
  for (int r = 0; r < 4; ++r) {
    float mx = fmaxf(fmaxf(accs[0][r], accs[1][r]), fmaxf(accs[2][r], accs[3][r]));
    mx = fmaxf(mx, __shfl_xor(mx, 1));
    mx = fmaxf(mx, __shfl_xor(mx, 2));
    mx = fmaxf(mx, __shfl_xor(mx, 4));
    mx = fmaxf(mx, __shfl_xor(mx, 8));
    float newm = fmaxf(m[r], mx);
    fs[r] = __builtin_amdgcn_exp2f(m[r] - newm);
    m[r] = newm;
  }
  #pragma unroll
  for (int nj = 0; nj < 4; ++nj)
    #pragma unroll
    for (int r = 0; r < 4; ++r)
      accs[nj][r] = __builtin_amdgcn_exp2f(accs[nj][r] - m[r]);
  #pragma unroll
  for (int r = 0; r < 4; ++r) {
    float s = (accs[0][r] + accs[1][r]) + (accs[2][r] + accs[3][r]);
    lp[r] = lp[r] * fs[r] + s;
    #pragma unroll
    for (int nj = 0; nj < 4; ++nj) acco[nj][r] *= fs[r];
  }
  #pragma unroll
  for (int nj = 0; nj < 4; ++nj)
    #pragma unroll
    for (int r = 0; r < 4; ++r) {
      int tr = g * 4 + r;
      Pst[(tr * 64 + nj * 16 + c) ^ ((tr & 7) << 3)] = f2bf(accs[nj][r]);
    }
}

// ------------------------------------------------------------- flash attention
// Dual-strip ILP: each wave owns strips (p, 63-p); ONE shared k-loop loads each
// K/V tile once and runs BOTH strips' independent QK/softmax/PV chains
// interleaved (2x ILP to cover the serial chain). XCD remap keeps each bh's
// K/V on one XCD's L2. launch_bounds(256,3): VGPR cap 170 (3 waves/SIMD, the
// grid-given occupancy) -- R4's spill came from the 128 cap; live set ~150.
__global__ __launch_bounds__(256, 3) void attn(const unsigned short* __restrict__ qb,
                                               const unsigned short* __restrict__ kb,
                                               const unsigned short* __restrict__ vT,
                                               unsigned short* __restrict__ ao) {
  __shared__ unsigned short P[4][2][16 * 64];
  int bid0 = blockIdx.x;
  // remap: bid = sub*96 + m12*8 + xcd -> all 8 sub-blocks of bh=(xcd*12+m12)
  // land on the same XCD under round-robin dispatch. Bijective on 768.
  int xcd = bid0 & 7, slot = bid0 >> 3;
  int m12 = slot % 12, sub = slot / 12;
  int bh = xcd * 12 + m12;
  int b = bh / HH, h = bh % HH;
  int t = threadIdx.x, lane = t & 63, w = t >> 6;
  int g = lane >> 4, c = lane & 15;
  unsigned short* PA = P[w][0];
  unsigned short* PB = P[w][1];
  const unsigned short* Q = qb + (size_t)bh * TT * DD;
  const unsigned short* K = kb + (size_t)bh * TT * DD;
  const unsigned short* V = vT + (size_t)bh * DD * TT;
  int p = sub * 4 + w;                 // 0..31
  int qA = p * 16, qB = (63 - p) * 16; // strip A short, strip B long
  int ntA = (qA + 79) >> 6, ntB = (qB + 79) >> 6;  // ntA+ntB == 17 for all p

  s16x8 aqA[2], aqB[2];
  #pragma unroll
  for (int ks = 0; ks < 2; ++ks) {
    aqA[ks] = *(const s16x8*)(Q + (size_t)(qA + c) * DD + ks * 32 + g * 8);
    aqB[ks] = *(const s16x8*)(Q + (size_t)(qB + c) * DD + ks * 32 + g * 8);
  }

  f32x4 accoA[4], accoB[4];
  float mA[4], lA[4], mB[4], lB[4];
  #pragma unroll
  for (int nj = 0; nj < 4; ++nj) {
    accoA[nj] = (f32x4){0.f, 0.f, 0.f, 0.f};
    accoB[nj] = (f32x4){0.f, 0.f, 0.f, 0.f};
  }
  #pragma unroll
  for (int r = 0; r < 4; ++r) {
    mA[r] = -1e30f; lA[r] = 0.f;
    mB[r] = -1e30f; lB[r] = 0.f;
  }

  #pragma unroll 1
  for (int kt = 0; kt < ntB; ++kt) {
    int s0 = kt * 64;
    bool dual = (kt < ntA);
    f32x4 accsA[4], accsB[4];
    #pragma unroll
    for (int nj = 0; nj < 4; ++nj) {
      accsA[nj] = (f32x4){0.f, 0.f, 0.f, 0.f};
      accsB[nj] = (f32x4){0.f, 0.f, 0.f, 0.f};
    }

    // S = Q K^T for both strips off ONE K-tile load (bk transient)
    #pragma unroll
    for (int ks = 0; ks < 2; ++ks) {
      s16x8 bk[4];
      #pragma unroll
      for (int nj = 0; nj < 4; ++nj)
        bk[nj] = *(const s16x8*)(K + (size_t)(s0 + nj * 16 + c) * DD + ks * 32 + g * 8);
      #pragma unroll
      for (int nj = 0; nj < 4; ++nj)
        accsB[nj] = __builtin_amdgcn_mfma_f32_16x16x32_bf16(aqB[ks], bk[nj],
                                                            accsB[nj], 0, 0, 0);
      if (dual) {
        #pragma unroll
        for (int nj = 0; nj < 4; ++nj)
          accsA[nj] = __builtin_amdgcn_mfma_f32_16x16x32_bf16(aqA[ks], bk[nj],
                                                              accsA[nj], 0, 0, 0);
      }
    }

    // V loads issued early: latency hides under the two softmax chains
    s16x8 bv[2][4];
    #pragma unroll
    for (int ks = 0; ks < 2; ++ks)
      #pragma unroll
      for (int nj = 0; nj < 4; ++nj)
        bv[ks][nj] = *(const s16x8*)(V + (size_t)(nj * 16 + c) * TT +
                                     s0 + ks * 32 + g * 8);

    if (dual) softmax_tile(accsA, mA, lA, accoA, qA, s0, kt == ntA - 1, g, c, PA);
    softmax_tile(accsB, mB, lB, accoB, qB, s0, kt == ntB - 1, g, c, PB);
    asm volatile("" ::: "memory");  // P writes before P reads

    // O += P V for both strips off the shared V tile
    #pragma unroll
    for (int ks = 0; ks < 2; ++ks) {
      s16x8 paB = *(const s16x8*)(PB + ((c * 64 + ks * 32 + g * 8) ^ ((c & 7) << 3)));
      #pragma unroll
      for (int nj = 0; nj < 4; ++nj)
        accoB[nj] = __builtin_amdgcn_mfma_f32_16x16x32_bf16(paB, bv[ks][nj],
                                                            accoB[nj], 0, 0, 0);
    }
    if (dual) {
      #pragma unroll
      for (int ks = 0; ks < 2; ++ks) {
        s16x8 paA = *(const s16x8*)(PA + ((c * 64 + ks * 32 + g * 8) ^ ((c & 7) << 3)));
        #pragma unroll
        for (int nj = 0; nj < 4; ++nj)
          accoA[nj] = __builtin_amdgcn_mfma_f32_16x16x32_bf16(paA, bv[ks][nj],
                                                              accoA[nj], 0, 0, 0);
      }
    }
    asm volatile("" ::: "memory");
  }

  // epilogue: deferred l-reduction (once per strip) + O/l writeback
  #pragma unroll
  for (int r = 0; r < 4; ++r) {
    float sA = lA[r];
    sA += __shfl_xor(sA, 1);
    sA += __shfl_xor(sA, 2);
    sA += __shfl_xor(sA, 4);
    sA += __shfl_xor(sA, 8);
    float invA = 1.0f / sA;
    int trA = qA + g * 4 + r;
    size_t rowbA = ((size_t)b * TT + trA) * CC + h * DD;
    #pragma unroll
    for (int nj = 0; nj < 4; ++nj)
      ao[rowbA + nj * 16 + c] = f2bf(accoA[nj][r] * invA);

    float sB = lB[r];
    sB += __shfl_xor(sB, 1);
    sB += __shfl_xor(sB, 2);
    sB += __shfl_xor(sB, 4);
    sB += __shfl_xor(sB, 8);
    float invB = 1.0f / sB;
    int trB = qB + g * 4 + r;
    size_t rowbB = ((size_t)b * TT + trB) * CC + h * DD;
    #pragma unroll
    for (int nj = 0; nj < 4; ++nj)
      ao[rowbB + nj * 16 + c] = f2bf(accoB[nj][r] * invB);
  }
}

// -------------------------------------------------------- output projection
__global__ __launch_bounds__(256) void gemm_proj(const unsigned short* __restrict__ ao,
                                                 const unsigned short* __restrict__ WpB,
                                                 const float* __restrict__ bp,
                                                 float* __restrict__ out) {
  __shared__ unsigned short As[128 * 64], Bs[128 * 64];
  int bid = blockIdx.x;
  int bm = bid % 64, bn = bid / 64;
  int m0 = bm * 128, n0 = bn * 128;
  f32x4 acc[4][4];
  #pragma unroll
  for (int i = 0; i < 4; ++i)
    #pragma unroll
    for (int j = 0; j < 4; ++j)
      acc[i][j] = (f32x4){0.f, 0.f, 0.f, 0.f};
  gemm_tile(ao, WpB, m0, n0, As, Bs, acc);

  const int t = threadIdx.x, lane = t & 63, w = t >> 6;
  const int g = lane >> 4, c = lane & 15;
  const int wr = w >> 1, wc = w & 1;
  #pragma unroll
  for (int i = 0; i < 4; ++i) {
    int mrow = m0 + wr * 64 + i * 16 + g * 4;
    #pragma unroll
    for (int j = 0; j < 4; ++j) {
      int nn = n0 + wc * 64 + j * 16 + c;
      float bias = bp[nn];
      float* dst = out + (size_t)mrow * CC + nn;
      dst[0]        = acc[i][j][0] + bias;
      dst[CC]       = acc[i][j][1] + bias;
      dst[2 * CC]   = acc[i][j][2] + bias;
      dst[3 * CC]   = acc[i][j][3] + bias;
    }
  }
}

// ------------------------------------------------------------------- launcher
extern "C" void kernel_launch(void* const* d_in, const int* in_sizes, int n_in,
                              void* d_out, int out_size, void* d_ws, size_t ws_size,
                              hipStream_t stream) {
  (void)in_sizes; (void)n_in; (void)out_size; (void)ws_size;
  const float* x  = (const float*)d_in[0];
  const float* Wq = (const float*)d_in[1];
  const float* Wk = (const float*)d_in[2];
  const float* Wv = (const float*)d_in[3];
  const float* Wp = (const float*)d_in[4];
  const float* bp = (const float*)d_in[5];
  float* out = (float*)d_out;

  char* ws = (char*)d_ws;
  unsigned short* xb  = (unsigned short*)(ws);                       // 8192x768
  unsigned short* WT  = (unsigned short*)(ws + 12582912);            // 2304x768
  unsigned short* WpB = (unsigned short*)(ws + 16121856);            // 768x768
  unsigned short* qb  = (unsigned short*)(ws + 17301504);            // [B][H][T][D]
  unsigned short* kb  = (unsigned short*)(ws + 29884416);            // [B][H][T][D]
  unsigned short* vT  = (unsigned short*)(ws + 42467328);            // [B][H][D][T]
  unsigned short* aob = (unsigned short*)(ws + 55050240);            // 8192x768
  // total = 67633152 bytes

  cast_f32_bf16<<<6144, 256, 0, stream>>>(x, xb, 1572864);
  cast_f32_bf16<<<576, 256, 0, stream>>>(Wp, WpB, 147456);
  transpose_w<<<1728, 256, 0, stream>>>(Wq, Wk, Wv, WT);
  gemm_qkv<<<1152, 256, 0, stream>>>(xb, WT, qb, kb, vT);
  attn<<<768, 256, 0, stream>>>(qb, kb, vT, aob);
  gemm_proj<<<384, 256, 0, stream>>>(aob, WpB, bp, out);
}